// Round 5
// baseline (108.950 us; speedup 1.0000x reference)
//
#include <hip/hip_runtime.h>

// B=16,S=38 -> ROWS=608; D=1792; H=4, DK=448; NP=128; INF=768
#define TM 128
#define TN 128
#define BK 16
#define LDT 132   // padded LDS leading dim (floats): 132*4=528 B, 16B-aligned

struct SP {
    const float *p0, *p1, *p2, *p3, *p4, *p5, *p6, *p7;
    float *q0, *q1, *q2;
};

__device__ __forceinline__ float wave_sum(float v) {
    #pragma unroll
    for (int off = 32; off; off >>= 1) v += __shfl_down(v, off);
    return v;
}

// out[m*2+c] = A[m,:] @ W[:,c]  (W row-major [K][2]); K % 256 == 0
__device__ __forceinline__ void colvec2_unit(
    const float* __restrict__ A, int lda, const float* __restrict__ W,
    float* __restrict__ out, int K, int m, int lane)
{
    const float4* a = (const float4*)(A + (long)m * lda);
    float a0 = 0.f, a1 = 0.f;
    for (int i = 0; i < K / 256; ++i) {
        const int d4 = lane + 64 * i;
        float4 xv = a[d4];
        const float4* w = (const float4*)(W + (long)d4 * 8);
        float4 w0 = w[0], w1 = w[1];
        a0 += xv.x*w0.x + xv.y*w0.z + xv.z*w1.x + xv.w*w1.z;
        a1 += xv.x*w0.y + xv.y*w0.w + xv.z*w1.y + xv.w*w1.w;
    }
    a0 = wave_sum(a0); a1 = wave_sum(a1);
    if (lane == 0) { out[m * 2 + 0] = a0; out[m * 2 + 1] = a1; }
}

// sbias[unit] = dot(bq_h, Kp[p]_h) over 448, unit = h*128+p
__device__ __forceinline__ void sbias_unit(
    const float* __restrict__ bq, const float* __restrict__ Kp,
    float* __restrict__ sb, int unit, int lane)
{
    const int h = unit >> 7, p = unit & 127;
    const float* kr = Kp + (long)p * 1792 + h * 448;
    const float* bh = bq + h * 448;
    float s = 0.f;
    #pragma unroll
    for (int i = 0; i < 7; ++i) s = fmaf(bh[lane + 64 * i], kr[lane + 64 * i], s);
    s = wave_sum(s);
    if (lane == 0) sb[unit] = s;
}

// WvWoQ[h][d][c] = sum_{j<448} Wv[d][h*448+j] * WoQ[(h*448+j)*2+c]
__device__ __forceinline__ void wvwoq_unit(
    const float* __restrict__ Wv, const float* __restrict__ WoQ,
    float* __restrict__ out, int d, int h, int lane)
{
    const float* wr = Wv + (long)d * 1792 + h * 448;
    const float* wq = WoQ + h * 448 * 2;
    float s0 = 0.f, s1 = 0.f;
    #pragma unroll
    for (int i = 0; i < 7; ++i) {
        const int j = lane + 64 * i;
        const float v = wr[j];
        s0 = fmaf(v, wq[j * 2 + 0], s0);
        s1 = fmaf(v, wq[j * 2 + 1], s1);
    }
    s0 = wave_sum(s0); s1 = wave_sum(s1);
    if (lane == 0) {
        out[((long)h * 1792 + d) * 2 + 0] = s0;
        out[((long)h * 1792 + d) * 2 + 1] = s1;
    }
}

// units 0..3: cv[h] = bv_h @ WoQ_h ; unit 4: const2 = bqa + bfc@Wqa + bo@WfbQ
__device__ __forceinline__ void bias_unit(
    const float* __restrict__ bv, const float* __restrict__ WoQ,
    const float* __restrict__ bfc, const float* __restrict__ Wqa,
    const float* __restrict__ bo, const float* __restrict__ WfbQ,
    const float* __restrict__ bqa,
    float* __restrict__ cv, float* __restrict__ const2, int unit, int lane)
{
    float s0 = 0.f, s1 = 0.f;
    if (unit < 4) {
        const int h = unit;
        #pragma unroll
        for (int i = 0; i < 7; ++i) {
            const int j = h * 448 + lane + 64 * i;
            const float v = bv[j];
            s0 = fmaf(v, WoQ[j * 2 + 0], s0);
            s1 = fmaf(v, WoQ[j * 2 + 1], s1);
        }
    } else {
        for (int k = lane; k < 1792; k += 64) {
            if (k < 768) {
                s0 = fmaf(bfc[k], Wqa[k * 2 + 0], s0);
                s1 = fmaf(bfc[k], Wqa[k * 2 + 1], s1);
            }
            s0 = fmaf(bo[k], WfbQ[k * 2 + 0], s0);
            s1 = fmaf(bo[k], WfbQ[k * 2 + 1], s1);
        }
    }
    s0 = wave_sum(s0); s1 = wave_sum(s1);
    if (lane == 0) {
        if (unit < 4) { cv[unit * 2 + 0] = s0; cv[unit * 2 + 1] = s1; }
        else          { const2[0] = s0 + bqa[0]; const2[1] = s1 + bqa[1]; }
    }
}

// C = A[M,K] @ op(B); split-K partials [kb][bb][M][N]; batch bb via pointer strides.
// z < mainZ: gemm blocks (kb = z%nsplit, bb = z/nsplit). z >= mainZ: side tasks.
template<bool TRANSB, int SIDE>
__global__ __launch_bounds__(256) void gemm_f32(
    const float* __restrict__ A, int lda,
    const float* __restrict__ B, int ldb,
    float* __restrict__ C, int ldc,
    int M, int N, int K,
    int nsplit, int nbb, int mainZ,
    long sAb, long sBb, long sCb, SP sp)
{
    const int tid = threadIdx.x;
    if ((int)blockIdx.z >= mainZ) {
        const int bid = ((int)blockIdx.z - mainZ) * (gridDim.x * gridDim.y)
                      + blockIdx.y * gridDim.x + blockIdx.x;
        const int lane = tid & 63;
        const int u = bid * 4 + (tid >> 6);
        if constexpr (SIDE == 1) {
            // colvec2: Wfc[3584x768] @ Wqa -> WbigB
            if (u < 3584) colvec2_unit(sp.p0, 768, sp.p1, sp.q0, 768, u, lane);
        } else if constexpr (SIDE == 2) {
            // colvec2: Wo[1792x1792] @ WfbQ -> WoQ ; sbias
            if (u < 1792)       colvec2_unit(sp.p0, 1792, sp.p1, sp.q0, 1792, u, lane);
            else if (u < 2304)  sbias_unit(sp.p2, sp.p3, sp.q1, u - 1792, lane);
        } else if constexpr (SIDE == 3) {
            // wvwoq (7168 units) ; bias (5 units)
            if (u < 7168)       wvwoq_unit(sp.p0, sp.p1, sp.q0, u % 1792, u / 1792, lane);
            else if (u < 7173)  bias_unit(sp.p2, sp.p1, sp.p3, sp.p4, sp.p5, sp.p6, sp.p7,
                                          sp.q1, sp.q2, u - 7168, lane);
        }
        return;
    }

    const int kb = blockIdx.z % nsplit;
    const int bb = blockIdx.z / nsplit;
    A += sAb * bb;
    B += sBb * bb;
    const int Kc = K / nsplit;
    const int kbeg = kb * Kc;

    __shared__ float As[2][BK][LDT];
    __shared__ float Bs[2][BK][LDT];

    const int tx = tid & 15, ty = tid >> 4;
    const int rowBase = blockIdx.y * TM;
    const int colBase = blockIdx.x * TN;

    // staging maps
    const int ar  = tid >> 2;           // A row 0..63 (and +64)
    const int akq = (tid & 3) * 4;      // A k-quad
    const int bkr = tid >> 4;           // B k-row (TRANSB=false) 0..15
    const int bc8 = (tid & 15) * 8;     // B col-oct
    const int bn  = tid >> 2;           // B n-row (TRANSB=true) 0..63 (and +64)
    const int bkq = (tid & 3) * 4;

    const int row0 = rowBase + ar, row1 = row0 + 64;
    const bool aok0 = row0 < M, aok1 = row1 < M;

    float4 av0, av1, bv0, bv1;
    auto loadA = [&](int k0) {
        av0 = make_float4(0.f, 0.f, 0.f, 0.f);
        av1 = av0;
        if (aok0) av0 = *(const float4*)&A[(long)row0 * lda + k0 + akq];
        if (aok1) av1 = *(const float4*)&A[(long)row1 * lda + k0 + akq];
    };
    auto loadB = [&](int k0) {
        if (!TRANSB) {
            bv0 = *(const float4*)&B[(long)(k0 + bkr) * ldb + colBase + bc8];
            bv1 = *(const float4*)&B[(long)(k0 + bkr) * ldb + colBase + bc8 + 4];
        } else {
            bv0 = *(const float4*)&B[(long)(colBase + bn) * ldb + k0 + bkq];
            bv1 = *(const float4*)&B[(long)(colBase + bn + 64) * ldb + k0 + bkq];
        }
    };
    auto stage = [&](int buf) {
        As[buf][akq + 0][ar] = av0.x; As[buf][akq + 1][ar] = av0.y;
        As[buf][akq + 2][ar] = av0.z; As[buf][akq + 3][ar] = av0.w;
        As[buf][akq + 0][ar + 64] = av1.x; As[buf][akq + 1][ar + 64] = av1.y;
        As[buf][akq + 2][ar + 64] = av1.z; As[buf][akq + 3][ar + 64] = av1.w;
        if (!TRANSB) {
            *(float4*)&Bs[buf][bkr][bc8] = bv0;
            *(float4*)&Bs[buf][bkr][bc8 + 4] = bv1;
        } else {
            Bs[buf][bkq + 0][bn] = bv0.x; Bs[buf][bkq + 1][bn] = bv0.y;
            Bs[buf][bkq + 2][bn] = bv0.z; Bs[buf][bkq + 3][bn] = bv0.w;
            Bs[buf][bkq + 0][bn + 64] = bv1.x; Bs[buf][bkq + 1][bn + 64] = bv1.y;
            Bs[buf][bkq + 2][bn + 64] = bv1.z; Bs[buf][bkq + 3][bn + 64] = bv1.w;
        }
    };

    float acc[8][8] = {};
    loadA(kbeg); loadB(kbeg);
    stage(0);
    __syncthreads();

    const int nk = Kc / BK;
    for (int t = 0; t < nk; ++t) {
        const int cur = t & 1;
        const bool more = (t + 1 < nk);
        if (more) { loadA(kbeg + (t + 1) * BK); loadB(kbeg + (t + 1) * BK); }
        #pragma unroll
        for (int kk = 0; kk < BK; ++kk) {
            float a[8], b[8];
            *(float4*)&a[0] = *(const float4*)&As[cur][kk][ty * 8];
            *(float4*)&a[4] = *(const float4*)&As[cur][kk][ty * 8 + 4];
            *(float4*)&b[0] = *(const float4*)&Bs[cur][kk][tx * 8];
            *(float4*)&b[4] = *(const float4*)&Bs[cur][kk][tx * 8 + 4];
            #pragma unroll
            for (int i = 0; i < 8; ++i)
                #pragma unroll
                for (int j = 0; j < 8; ++j)
                    acc[i][j] = fmaf(a[i], b[j], acc[i][j]);
        }
        if (more) stage(cur ^ 1);
        __syncthreads();
    }

    float* Cw; int wldc;
    if (nsplit > 1) { Cw = C + ((long)kb * nbb + bb) * (long)M * N; wldc = N; }
    else            { Cw = C + sCb * bb; wldc = ldc; }
    #pragma unroll
    for (int i = 0; i < 8; ++i) {
        const int row = rowBase + ty * 8 + i;
        if (row >= M) continue;
        *(float4*)&Cw[(long)row * wldc + colBase + tx * 8] =
            make_float4(acc[i][0], acc[i][1], acc[i][2], acc[i][3]);
        *(float4*)&Cw[(long)row * wldc + colBase + tx * 8 + 4] =
            make_float4(acc[i][4], acc[i][5], acc[i][6], acc[i][7]);
    }
}

// out[i] = sum_z part[z*sz+i] (+ bias[i%N])
__global__ __launch_bounds__(256) void reduce_add(
    const float* __restrict__ part, float* __restrict__ out,
    const float* __restrict__ bias, int N, long sz, int nsplit)
{
    long i = (long)blockIdx.x * 256 + threadIdx.x;
    const long stride = (long)gridDim.x * 256;
    for (; i < sz; i += stride) {
        float s = 0.f;
        for (int z = 0; z < nsplit; ++z) s += part[z * sz + i];
        if (bias) s += bias[i % N];
        out[i] = s;
    }
}

// blocks 0..607: per (row,h) sum 8 K-split partials + sbias -> argmax index
// blocks 608..735: LG[h][p] = proto[p] @ WvWoQ[h] + cv[h]
__global__ __launch_bounds__(256) void argmax_lg_k(
    const float* __restrict__ Sp,      // [8][4][608][128]
    const float* __restrict__ sbias,   // [4][128]
    int* __restrict__ idx,             // [608][4]
    const float* __restrict__ proto, const float* __restrict__ WvWoQ,
    const float* __restrict__ cv, float* __restrict__ LG)
{
    const int lane = threadIdx.x & 63;
    const int b = blockIdx.x;
    if (b < 608) {
        const int unit = b * 4 + (threadIdx.x >> 6);
        const int row = unit >> 2, h = unit & 3;
        float s0 = sbias[h * 128 + lane];
        float s1 = sbias[h * 128 + lane + 64];
        #pragma unroll
        for (int z = 0; z < 8; ++z) {
            const long base = ((long)(z * 4 + h) * 608 + row) * 128;
            s0 += Sp[base + lane];
            s1 += Sp[base + lane + 64];
        }
        float best = s0; int bi = lane;
        if (s1 > best) { best = s1; bi = lane + 64; }
        #pragma unroll
        for (int off = 32; off; off >>= 1) {
            float ov = __shfl_down(best, off);
            int   oi = __shfl_down(bi, off);
            if (ov > best || (ov == best && oi < bi)) { best = ov; bi = oi; }
        }
        if (lane == 0) idx[row * 4 + h] = bi;
    } else {
        const int unit = (b - 608) * 4 + (threadIdx.x >> 6);   // 0..511
        const int h = unit >> 7, p = unit & 127;
        const float4* a = (const float4*)(proto + (long)p * 1792);
        const float* W = WvWoQ + (long)h * 1792 * 2;
        float a0 = 0.f, a1 = 0.f;
        #pragma unroll
        for (int i = 0; i < 7; ++i) {
            const int d4 = lane + 64 * i;
            float4 xv = a[d4];
            const float4* w = (const float4*)(W + (long)d4 * 8);
            float4 w0 = w[0], w1 = w[1];
            a0 += xv.x*w0.x + xv.y*w0.z + xv.z*w1.x + xv.w*w1.z;
            a1 += xv.x*w0.y + xv.y*w0.w + xv.z*w1.y + xv.w*w1.w;
        }
        a0 = wave_sum(a0); a1 = wave_sum(a1);
        if (lane == 0) {
            LG[(h * 128 + p) * 2 + 0] = a0 + cv[h * 2 + 0];
            LG[(h * 128 + p) * 2 + 1] = a1 + cv[h * 2 + 1];
        }
    }
}

// logits[row][c] = X[row]@Wbig[:,c] + sum_h LG[h][idx[row][h]][c] + const2[c]
__global__ __launch_bounds__(256) void final_k(
    const float* __restrict__ X, const float* __restrict__ Wbig,
    const float* __restrict__ LG, const int* __restrict__ idx,
    const float* __restrict__ const2, float* __restrict__ out)
{
    const int lane = threadIdx.x & 63;
    const int row = blockIdx.x * 4 + (threadIdx.x >> 6);
    if (row >= 608) return;
    const float4* x = (const float4*)(X + (long)row * 1792);
    float a0 = 0.f, a1 = 0.f;
    #pragma unroll
    for (int i = 0; i < 7; ++i) {
        const int d4 = lane + 64 * i;
        float4 xv = x[d4];
        const float4* w = (const float4*)(Wbig + (long)d4 * 8);
        float4 w0 = w[0], w1 = w[1];
        a0 += xv.x*w0.x + xv.y*w0.z + xv.z*w1.x + xv.w*w1.z;
        a1 += xv.x*w0.y + xv.y*w0.w + xv.z*w1.y + xv.w*w1.w;
    }
    a0 = wave_sum(a0); a1 = wave_sum(a1);
    if (lane == 0) {
        float r0 = a0 + const2[0], r1 = a1 + const2[1];
        #pragma unroll
        for (int h = 0; h < 4; ++h) {
            const int p = idx[row * 4 + h];
            r0 += LG[(h * 128 + p) * 2 + 0];
            r1 += LG[(h * 128 + p) * 2 + 1];
        }
        out[row * 2 + 0] = r0;
        out[row * 2 + 1] = r1;
    }
}

extern "C" void kernel_launch(void* const* d_in, const int* in_sizes, int n_in,
                              void* d_out, int out_size, void* d_ws, size_t ws_size,
                              hipStream_t stream)
{
    const float* X     = (const float*)d_in[0];   // [608,1792]
    const float* proto = (const float*)d_in[1];   // [128,1792]
    const float* Wq  = (const float*)d_in[3];
    const float* bq  = (const float*)d_in[4];
    const float* Wk  = (const float*)d_in[5];
    const float* bk  = (const float*)d_in[6];
    const float* Wv  = (const float*)d_in[7];
    const float* bv  = (const float*)d_in[8];
    const float* Wo  = (const float*)d_in[9];
    const float* bo  = (const float*)d_in[10];
    const float* Wfc = (const float*)d_in[11];    // [3584,768]
    const float* bfc = (const float*)d_in[12];
    const float* Wqa = (const float*)d_in[13];    // [768,2]
    const float* bqa = (const float*)d_in[14];
    float* out = (float*)d_out;

    // workspace (floats)
    float* ws = (float*)d_ws;
    float* P      = ws;                 // 3,670,016 max partials (reused per phase)
    float* Kp     = P + 3670016;        // 229,376  [128][1792]
    float* W2b    = Kp + 229376;        // 917,504  [4][1792][128]
    float* sbias  = W2b + 917504;       // 512
    float* WbigB  = sbias + 512;        // 7,168    [3584][2] (top=Wbig, bottom=WfbQ)
    float* WoQ    = WbigB + 7168;       // 3,584    [1792][2]
    float* WvWoQ  = WoQ + 3584;         // 14,336   [4][1792][2]
    float* LG     = WvWoQ + 14336;      // 1,024    [4][128][2]
    float* cv     = LG + 1024;          // 8
    float* const2 = cv + 8;             // 2 (+6 pad)
    int*   idx    = (int*)(const2 + 8); // 2,432 ints
    float* WfbQ   = WbigB + 1792 * 2;

    dim3 blk(256);

    // L1: Kp partials = proto @ Wk  [split 16] ; side: WbigB = Wfc @ Wqa (896 blocks)
    {
        SP sp{}; sp.p0 = Wfc; sp.p1 = Wqa; sp.q0 = WbigB;
        gemm_f32<false, 1><<<dim3(14, 1, 16 + 64), blk, 0, stream>>>(
            proto, 1792, Wk, 1792, P, 0, 128, 1792, 1792, 16, 1, 16, 0, 0, 0, sp);
    }
    // L2: Kp = sum partials + bk
    reduce_add<<<dim3(896), blk, 0, stream>>>(P, Kp, bk, 1792, 229376L, 16);

    // L3: W2 partials = Wq_h @ Kp_h^T  [batch 4, split 4] ; side: WoQ = Wo@WfbQ (448) + sbias (128)
    {
        SP sp{}; sp.p0 = Wo; sp.p1 = WfbQ; sp.q0 = WoQ; sp.p2 = bq; sp.p3 = Kp; sp.q1 = sbias;
        gemm_f32<true, 2><<<dim3(1, 14, 16 + 42), blk, 0, stream>>>(
            Wq, 1792, Kp, 1792, P, 0, 1792, 128, 448, 4, 4, 16, 448, 448, 0, sp);
    }
    // L4: W2b = sum partials
    reduce_add<<<dim3(1024), blk, 0, stream>>>(P, W2b, nullptr, 1, 917504L, 4);

    // L5: Sc partials = X @ W2b[h]  [batch 4, split 8] ; side: WvWoQ (1792) + bias (2)
    {
        SP sp{}; sp.p0 = Wv; sp.p1 = WoQ; sp.q0 = WvWoQ;
        sp.p2 = bv; sp.p3 = bfc; sp.p4 = Wqa; sp.p5 = bo; sp.p6 = WfbQ; sp.p7 = bqa;
        sp.q1 = cv; sp.q2 = const2;
        gemm_f32<false, 3><<<dim3(1, 5, 32 + 359), blk, 0, stream>>>(
            X, 1792, W2b, 128, P, 0, 608, 128, 1792, 8, 4, 32, 0, 229376L, 0, sp);
    }
    // L6: argmax per (row,head) + LG tables
    argmax_lg_k<<<dim3(736), blk, 0, stream>>>(P, sbias, idx, proto, WvWoQ, cv, LG);

    // L7: logits
    final_k<<<dim3(152), blk, 0, stream>>>(X, WbigB, LG, idx, const2, out);
}

// Round 6
// 99.562 us; speedup vs baseline: 1.0943x; 1.0943x over previous
//
#include <hip/hip_runtime.h>

// B=16,S=38 -> ROWS=608; D=1792; H=4, DK=448; NP=128; INF=768
#define TM 128
#define TN 128
#define BK 16
#define LDT 132   // padded LDS leading dim (floats): 132*4=528 B, 16B-aligned rows

struct SP {
    const float *p0, *p1, *p2, *p3, *p4, *p5, *p6, *p7;
    float *q0, *q1, *q2;
};

__device__ __forceinline__ float wave_sum(float v) {
    #pragma unroll
    for (int off = 32; off; off >>= 1) v += __shfl_down(v, off);
    return v;
}

// out[m*2+c] = A[m,:] @ W[:,c]  (W row-major [K][2]); K % 256 == 0
__device__ __forceinline__ void colvec2_unit(
    const float* __restrict__ A, int lda, const float* __restrict__ W,
    float* __restrict__ out, int K, int m, int lane)
{
    const float4* a = (const float4*)(A + (long)m * lda);
    float a0 = 0.f, a1 = 0.f;
    for (int i = 0; i < K / 256; ++i) {
        const int d4 = lane + 64 * i;
        float4 xv = a[d4];
        const float4* w = (const float4*)(W + (long)d4 * 8);
        float4 w0 = w[0], w1 = w[1];
        a0 += xv.x*w0.x + xv.y*w0.z + xv.z*w1.x + xv.w*w1.z;
        a1 += xv.x*w0.y + xv.y*w0.w + xv.z*w1.y + xv.w*w1.w;
    }
    a0 = wave_sum(a0); a1 = wave_sum(a1);
    if (lane == 0) { out[m * 2 + 0] = a0; out[m * 2 + 1] = a1; }
}

// sbias[unit] = dot(bq_h, Kp[p]_h) over 448, unit = h*128+p
__device__ __forceinline__ void sbias_unit(
    const float* __restrict__ bq, const float* __restrict__ Kp,
    float* __restrict__ sb, int unit, int lane)
{
    const int h = unit >> 7, p = unit & 127;
    const float* kr = Kp + (long)p * 1792 + h * 448;
    const float* bh = bq + h * 448;
    float s = 0.f;
    #pragma unroll
    for (int i = 0; i < 7; ++i) s = fmaf(bh[lane + 64 * i], kr[lane + 64 * i], s);
    s = wave_sum(s);
    if (lane == 0) sb[unit] = s;
}

// WvWoQ[h][d][c] = sum_{j<448} Wv[d][h*448+j] * WoQ[(h*448+j)*2+c]
__device__ __forceinline__ void wvwoq_unit(
    const float* __restrict__ Wv, const float* __restrict__ WoQ,
    float* __restrict__ out, int d, int h, int lane)
{
    const float* wr = Wv + (long)d * 1792 + h * 448;
    const float* wq = WoQ + h * 448 * 2;
    float s0 = 0.f, s1 = 0.f;
    #pragma unroll
    for (int i = 0; i < 7; ++i) {
        const int j = lane + 64 * i;
        const float v = wr[j];
        s0 = fmaf(v, wq[j * 2 + 0], s0);
        s1 = fmaf(v, wq[j * 2 + 1], s1);
    }
    s0 = wave_sum(s0); s1 = wave_sum(s1);
    if (lane == 0) {
        out[((long)h * 1792 + d) * 2 + 0] = s0;
        out[((long)h * 1792 + d) * 2 + 1] = s1;
    }
}

// units 0..3: cv[h] = bv_h @ WoQ_h ; unit 4: const2 = bqa + bfc@Wqa + bo@WfbQ
__device__ __forceinline__ void bias_unit(
    const float* __restrict__ bv, const float* __restrict__ WoQ,
    const float* __restrict__ bfc, const float* __restrict__ Wqa,
    const float* __restrict__ bo, const float* __restrict__ WfbQ,
    const float* __restrict__ bqa,
    float* __restrict__ cv, float* __restrict__ const2, int unit, int lane)
{
    float s0 = 0.f, s1 = 0.f;
    if (unit < 4) {
        const int h = unit;
        #pragma unroll
        for (int i = 0; i < 7; ++i) {
            const int j = h * 448 + lane + 64 * i;
            const float v = bv[j];
            s0 = fmaf(v, WoQ[j * 2 + 0], s0);
            s1 = fmaf(v, WoQ[j * 2 + 1], s1);
        }
    } else {
        for (int k = lane; k < 1792; k += 64) {
            if (k < 768) {
                s0 = fmaf(bfc[k], Wqa[k * 2 + 0], s0);
                s1 = fmaf(bfc[k], Wqa[k * 2 + 1], s1);
            }
            s0 = fmaf(bo[k], WfbQ[k * 2 + 0], s0);
            s1 = fmaf(bo[k], WfbQ[k * 2 + 1], s1);
        }
    }
    s0 = wave_sum(s0); s1 = wave_sum(s1);
    if (lane == 0) {
        if (unit < 4) { cv[unit * 2 + 0] = s0; cv[unit * 2 + 1] = s1; }
        else          { const2[0] = s0 + bqa[0]; const2[1] = s1 + bqa[1]; }
    }
}

// C = A[M,K] @ op(B); ALWAYS writes split-K partials [kb*nbb+bb][M][N] at C.
// 512 threads, 128x128 tile, 8x4 microtile, double-buffered LDS.
// z < mainZ: gemm blocks (kb = z%nsplit, bb = z/nsplit). z >= mainZ: side tasks (8 units/block).
template<bool TRANSB, int SIDE>
__global__ __launch_bounds__(512) void gemm_f32(
    const float* __restrict__ A, int lda,
    const float* __restrict__ B, int ldb,
    float* __restrict__ C,
    int M, int N, int K,
    int nsplit, int nbb, int mainZ,
    long sAb, long sBb, SP sp)
{
    const int tid = threadIdx.x;
    if ((int)blockIdx.z >= mainZ) {
        const int bid = ((int)blockIdx.z - mainZ) * (gridDim.x * gridDim.y)
                      + blockIdx.y * gridDim.x + blockIdx.x;
        const int lane = tid & 63;
        const int u = bid * 8 + (tid >> 6);
        if constexpr (SIDE == 1) {
            // WbigB = Wfc[3584x768] @ Wqa (3584 units)
            if (u < 3584) colvec2_unit(sp.p0, 768, sp.p1, sp.q0, 768, u, lane);
        } else if constexpr (SIDE == 2) {
            // WoQ = Wo[1792x1792] @ WfbQ (1792 units) ; sbias (512 units)
            if (u < 1792)       colvec2_unit(sp.p0, 1792, sp.p1, sp.q0, 1792, u, lane);
            else if (u < 2304)  sbias_unit(sp.p2, sp.p3, sp.q1, u - 1792, lane);
        } else if constexpr (SIDE == 3) {
            // WvWoQ (7168 units) ; bias (5 units)
            if (u < 7168)       wvwoq_unit(sp.p0, sp.p1, sp.q0, u % 1792, u / 1792, lane);
            else if (u < 7173)  bias_unit(sp.p2, sp.p1, sp.p3, sp.p4, sp.p5, sp.p6, sp.p7,
                                          sp.q1, sp.q2, u - 7168, lane);
        }
        return;
    }

    const int kb = blockIdx.z % nsplit;
    const int bb = blockIdx.z / nsplit;
    A += sAb * bb;
    B += sBb * bb;
    const int Kc = K / nsplit;
    const int kbeg = kb * Kc;

    __shared__ float As[2][BK][LDT];
    __shared__ float Bs[2][BK][LDT];

    const int tx = tid & 31, ty = tid >> 5;        // micro: rows ty*8..+8, cols tx*4..+4
    const int rowBase = blockIdx.y * TM;
    const int colBase = blockIdx.x * TN;

    // staging maps (one float4 per thread per tile)
    const int ar  = tid >> 2;           // A row 0..127
    const int akq = (tid & 3) * 4;      // A k-quad
    const int bkr = tid >> 5;           // B k-row (!TRANSB) 0..15
    const int bc4 = (tid & 31) * 4;     // B col-quad
    const int bn  = tid >> 2;           // B n-row (TRANSB) 0..127
    const int bkq = (tid & 3) * 4;      // B k-quad (TRANSB)

    const int row0 = rowBase + ar;
    const bool aok = row0 < M;

    float4 av, bv;
    auto loadA = [&](int k0) {
        av = make_float4(0.f, 0.f, 0.f, 0.f);
        if (aok) av = *(const float4*)&A[(long)row0 * lda + k0 + akq];
    };
    auto loadB = [&](int k0) {
        if (!TRANSB) bv = *(const float4*)&B[(long)(k0 + bkr) * ldb + colBase + bc4];
        else         bv = *(const float4*)&B[(long)(colBase + bn) * ldb + k0 + bkq];
    };
    auto stage = [&](int buf) {
        As[buf][akq + 0][ar] = av.x; As[buf][akq + 1][ar] = av.y;
        As[buf][akq + 2][ar] = av.z; As[buf][akq + 3][ar] = av.w;
        if (!TRANSB) {
            *(float4*)&Bs[buf][bkr][bc4] = bv;
        } else {
            Bs[buf][bkq + 0][bn] = bv.x; Bs[buf][bkq + 1][bn] = bv.y;
            Bs[buf][bkq + 2][bn] = bv.z; Bs[buf][bkq + 3][bn] = bv.w;
        }
    };

    float acc[8][4] = {};
    loadA(kbeg); loadB(kbeg);
    stage(0);
    __syncthreads();

    const int nk = Kc / BK;
    for (int t = 0; t < nk; ++t) {
        const int cur = t & 1;
        const bool more = (t + 1 < nk);
        if (more) { loadA(kbeg + (t + 1) * BK); loadB(kbeg + (t + 1) * BK); }
        #pragma unroll
        for (int kk = 0; kk < BK; ++kk) {
            float a[8], b[4];
            *(float4*)&a[0] = *(const float4*)&As[cur][kk][ty * 8];
            *(float4*)&a[4] = *(const float4*)&As[cur][kk][ty * 8 + 4];
            *(float4*)&b[0] = *(const float4*)&Bs[cur][kk][tx * 4];
            #pragma unroll
            for (int i = 0; i < 8; ++i)
                #pragma unroll
                for (int j = 0; j < 4; ++j)
                    acc[i][j] = fmaf(a[i], b[j], acc[i][j]);
        }
        if (more) stage(cur ^ 1);
        __syncthreads();
    }

    float* Cw = C + ((long)kb * nbb + bb) * (long)M * N;
    #pragma unroll
    for (int i = 0; i < 8; ++i) {
        const int row = rowBase + ty * 8 + i;
        if (row >= M) continue;
        *(float4*)&Cw[(long)row * N + colBase + tx * 4] =
            make_float4(acc[i][0], acc[i][1], acc[i][2], acc[i][3]);
    }
}

// out[i] = sum_z part[z*sz+i] (+ bias[i%N])
__global__ __launch_bounds__(256) void reduce_add(
    const float* __restrict__ part, float* __restrict__ out,
    const float* __restrict__ bias, int N, long sz, int nsplit)
{
    long i = (long)blockIdx.x * 256 + threadIdx.x;
    const long stride = (long)gridDim.x * 256;
    for (; i < sz; i += stride) {
        float s = 0.f;
        for (int z = 0; z < nsplit; ++z) s += part[z * sz + i];
        if (bias) s += bias[i % N];
        out[i] = s;
    }
}

// blocks 0..607: per (row,h) sum 16 K-split partials + sbias -> argmax index
// blocks 608..735: LG[h][p] = proto[p] @ WvWoQ[h] + cv[h]
__global__ __launch_bounds__(256) void argmax_lg_k(
    const float* __restrict__ Sp,      // [16][4][608][128]
    const float* __restrict__ sbias,   // [4][128]
    int* __restrict__ idx,             // [608][4]
    const float* __restrict__ proto, const float* __restrict__ WvWoQ,
    const float* __restrict__ cv, float* __restrict__ LG)
{
    const int lane = threadIdx.x & 63;
    const int b = blockIdx.x;
    if (b < 608) {
        const int unit = b * 4 + (threadIdx.x >> 6);
        const int row = unit >> 2, h = unit & 3;
        float s0 = sbias[h * 128 + lane];
        float s1 = sbias[h * 128 + lane + 64];
        #pragma unroll
        for (int z = 0; z < 16; ++z) {
            const long base = ((long)(z * 4 + h) * 608 + row) * 128;
            s0 += Sp[base + lane];
            s1 += Sp[base + lane + 64];
        }
        float best = s0; int bi = lane;
        if (s1 > best) { best = s1; bi = lane + 64; }
        #pragma unroll
        for (int off = 32; off; off >>= 1) {
            float ov = __shfl_down(best, off);
            int   oi = __shfl_down(bi, off);
            if (ov > best || (ov == best && oi < bi)) { best = ov; bi = oi; }
        }
        if (lane == 0) idx[row * 4 + h] = bi;
    } else {
        const int unit = (b - 608) * 4 + (threadIdx.x >> 6);   // 0..511
        const int h = unit >> 7, p = unit & 127;
        const float4* a = (const float4*)(proto + (long)p * 1792);
        const float* W = WvWoQ + (long)h * 1792 * 2;
        float a0 = 0.f, a1 = 0.f;
        #pragma unroll
        for (int i = 0; i < 7; ++i) {
            const int d4 = lane + 64 * i;
            float4 xv = a[d4];
            const float4* w = (const float4*)(W + (long)d4 * 8);
            float4 w0 = w[0], w1 = w[1];
            a0 += xv.x*w0.x + xv.y*w0.z + xv.z*w1.x + xv.w*w1.z;
            a1 += xv.x*w0.y + xv.y*w0.w + xv.z*w1.y + xv.w*w1.w;
        }
        a0 = wave_sum(a0); a1 = wave_sum(a1);
        if (lane == 0) {
            LG[(h * 128 + p) * 2 + 0] = a0 + cv[h * 2 + 0];
            LG[(h * 128 + p) * 2 + 1] = a1 + cv[h * 2 + 1];
        }
    }
}

// logits[row][c] = X[row]@Wbig[:,c] + sum_h LG[h][idx[row][h]][c] + const2[c]
__global__ __launch_bounds__(256) void final_k(
    const float* __restrict__ X, const float* __restrict__ Wbig,
    const float* __restrict__ LG, const int* __restrict__ idx,
    const float* __restrict__ const2, float* __restrict__ out)
{
    const int lane = threadIdx.x & 63;
    const int row = blockIdx.x * 4 + (threadIdx.x >> 6);
    if (row >= 608) return;
    const float4* x = (const float4*)(X + (long)row * 1792);
    float a0 = 0.f, a1 = 0.f;
    #pragma unroll
    for (int i = 0; i < 7; ++i) {
        const int d4 = lane + 64 * i;
        float4 xv = x[d4];
        const float4* w = (const float4*)(Wbig + (long)d4 * 8);
        float4 w0 = w[0], w1 = w[1];
        a0 += xv.x*w0.x + xv.y*w0.z + xv.z*w1.x + xv.w*w1.z;
        a1 += xv.x*w0.y + xv.y*w0.w + xv.z*w1.y + xv.w*w1.w;
    }
    a0 = wave_sum(a0); a1 = wave_sum(a1);
    if (lane == 0) {
        float r0 = a0 + const2[0], r1 = a1 + const2[1];
        #pragma unroll
        for (int h = 0; h < 4; ++h) {
            const int p = idx[row * 4 + h];
            r0 += LG[(h * 128 + p) * 2 + 0];
            r1 += LG[(h * 128 + p) * 2 + 1];
        }
        out[row * 2 + 0] = r0;
        out[row * 2 + 1] = r1;
    }
}

extern "C" void kernel_launch(void* const* d_in, const int* in_sizes, int n_in,
                              void* d_out, int out_size, void* d_ws, size_t ws_size,
                              hipStream_t stream)
{
    const float* X     = (const float*)d_in[0];   // [608,1792]
    const float* proto = (const float*)d_in[1];   // [128,1792]
    const float* Wq  = (const float*)d_in[3];
    const float* bq  = (const float*)d_in[4];
    const float* Wk  = (const float*)d_in[5];
    const float* bk  = (const float*)d_in[6];
    const float* Wv  = (const float*)d_in[7];
    const float* bv  = (const float*)d_in[8];
    const float* Wo  = (const float*)d_in[9];
    const float* bo  = (const float*)d_in[10];
    const float* Wfc = (const float*)d_in[11];    // [3584,768]
    const float* bfc = (const float*)d_in[12];
    const float* Wqa = (const float*)d_in[13];    // [768,2]
    const float* bqa = (const float*)d_in[14];
    float* out = (float*)d_out;

    // workspace (floats)
    float* ws = (float*)d_ws;
    float* P      = ws;                 // up to 4,980,736 partials (reused per phase)
    float* Kp     = P + 4980736;        // 229,376  [128][1792]
    float* W2b    = Kp + 229376;        // 917,504  [4][1792][128]
    float* sbias  = W2b + 917504;       // 512
    float* WbigB  = sbias + 512;        // 7,168    [3584][2] (top=Wbig, bottom=WfbQ)
    float* WoQ    = WbigB + 7168;       // 3,584    [1792][2]
    float* WvWoQ  = WoQ + 3584;         // 14,336   [4][1792][2]
    float* LG     = WvWoQ + 14336;      // 1,024    [4][128][2]
    float* cv     = LG + 1024;          // 8
    float* const2 = cv + 8;             // 2 (+6 pad)
    int*   idx    = (int*)(const2 + 8); // 2,432 ints
    float* WfbQ   = WbigB + 1792 * 2;

    dim3 gblk(512), blk(256);

    // L1: Kp partials = proto @ Wk  [split 14 -> 196 gemm blocks]
    //     side: WbigB = Wfc @ Wqa  (3584 units, 448 bids -> 32 z-slices x 14)
    {
        SP sp{}; sp.p0 = Wfc; sp.p1 = Wqa; sp.q0 = WbigB;
        gemm_f32<false, 1><<<dim3(14, 1, 14 + 32), gblk, 0, stream>>>(
            proto, 1792, Wk, 1792, P, 128, 1792, 1792, 14, 1, 14, 0, 0, sp);
    }
    // L2: Kp = sum 14 partials + bk
    reduce_add<<<dim3(896), blk, 0, stream>>>(P, Kp, bk, 1792, 229376L, 14);

    // L3: W2 partials = Wq_h @ Kp_h^T  [batch 4, split 4 -> 224 blocks]
    //     side: WoQ = Wo@WfbQ (1792) + sbias (512) -> 288 bids -> 21 z x 14
    {
        SP sp{}; sp.p0 = Wo; sp.p1 = WfbQ; sp.q0 = WoQ; sp.p2 = bq; sp.p3 = Kp; sp.q1 = sbias;
        gemm_f32<true, 2><<<dim3(1, 14, 16 + 21), gblk, 0, stream>>>(
            Wq, 1792, Kp, 1792, P, 1792, 128, 448, 4, 4, 16, 448, 448, sp);
    }
    // L4: W2b = sum 4 partials
    reduce_add<<<dim3(1792), blk, 0, stream>>>(P, W2b, nullptr, 1, 917504L, 4);

    // L5: Sc partials = X @ W2b[h]  [batch 4, split 16 -> 320 blocks]
    //     side: WvWoQ (7168) + bias (5) -> 897 bids -> 180 z x 5
    {
        SP sp{}; sp.p0 = Wv; sp.p1 = WoQ; sp.q0 = WvWoQ;
        sp.p2 = bv; sp.p3 = bfc; sp.p4 = Wqa; sp.p5 = bo; sp.p6 = WfbQ; sp.p7 = bqa;
        sp.q1 = cv; sp.q2 = const2;
        gemm_f32<false, 3><<<dim3(1, 5, 64 + 180), gblk, 0, stream>>>(
            X, 1792, W2b, 128, P, 608, 128, 1792, 16, 4, 64, 0, 229376L, sp);
    }
    // L6: argmax per (row,head) + LG tables
    argmax_lg_k<<<dim3(736), blk, 0, stream>>>(P, sbias, idx, proto, WvWoQ, cv, LG);

    // L7: logits
    final_k<<<dim3(152), blk, 0, stream>>>(X, WbigB, LG, idx, const2, out);
}